// Round 1
// baseline (75.728 us; speedup 1.0000x reference)
//
#include <hip/hip_runtime.h>
#include <math.h>

#define ALPHA 0.3f
#define K_NBR 32

__device__ __forceinline__ float leaky_f(float x) { return x >= 0.f ? x : ALPHA * x; }

// Hout[n,h] = leaky( sum_c X[n,c] * Qw[c,h] + Qb[h] ),  X: N x 64, Qw: 64 x 64
__global__ __launch_bounds__(256) void k_dense64(const float* __restrict__ X,
                                                 const float* __restrict__ Qw,
                                                 const float* __restrict__ Qb,
                                                 float* __restrict__ Hout, int N)
{
    __shared__ float sQ[64 * 64];
    __shared__ float sX[4 * 64];
    const int tid  = threadIdx.x;
    const int wid  = tid >> 6;   // wave (node slot) 0..3
    const int lane = tid & 63;   // h
    const int nr   = blockIdx.x * 4 + wid;
    const int n    = nr < N ? nr : N - 1;
    const bool valid = nr < N;

    #pragma unroll
    for (int i = 0; i < 16; ++i)
        sQ[i * 256 + tid] = Qw[i * 256 + tid];
    sX[wid * 64 + lane] = X[(long long)n * 64 + lane];
    __syncthreads();

    float acc = Qb[lane];
    #pragma unroll
    for (int c = 0; c < 64; ++c)
        acc = fmaf(sX[wid * 64 + c], sQ[c * 64 + lane], acc);
    if (valid)
        Hout[(long long)n * 64 + lane] = leaky_f(acc);
}

// Per node n (one wave each, 4 nodes/block):
//   w_k   = weights[n, nbr[n,k]]            (mode 0: gather + cache; mode 1: read cache)
//   agg_h = sum_k w_k * Hbuf[nbr[n,k], h] / (sum_k w_k + 1e-6)
//   cat   = [X[n,:], agg]                    (128)
//   o_h   = leaky( sum_d cat[d] * Ww[d,h] + Wb[h] )
//   OUT[n,h] = o_h / (||o||_2 + 1e-6)
// Safe in-place (OUT may alias X): wave reads X[n,:] before writing OUT[n,:].
__global__ __launch_bounds__(256) void k_conv(const float* __restrict__ X,
                                              const float* __restrict__ Hbuf,
                                              const float* __restrict__ Wmat, // N x N
                                              const int*  __restrict__ nbr,   // N x 32
                                              float* __restrict__ wcache,     // N x 32 or null
                                              const float* __restrict__ Ww,   // 128 x 64
                                              const float* __restrict__ Wb,   // 64
                                              float* __restrict__ OUT,
                                              int N, int mode)
{
    __shared__ float sW[128 * 64];  // 32 KB
    __shared__ float sw[4][32];
    __shared__ int   snb[4][32];
    __shared__ float sx[4][64];
    __shared__ float sa[4][64];

    const int tid  = threadIdx.x;
    const int wid  = tid >> 6;
    const int lane = tid & 63;
    const int nr   = blockIdx.x * 4 + wid;
    const int n    = nr < N ? nr : N - 1;
    const bool valid = nr < N;

    #pragma unroll
    for (int i = 0; i < 32; ++i)
        sW[i * 256 + tid] = Ww[i * 256 + tid];

    sx[wid][lane] = X[(long long)n * 64 + lane];
    if (lane < K_NBR) {
        int id = nbr[n * K_NBR + lane];
        snb[wid][lane] = id;
        float w;
        if (mode == 0) {
            w = Wmat[(long long)n * N + id];
            if (wcache && valid) wcache[n * K_NBR + lane] = w;
        } else {
            w = wcache[n * K_NBR + lane];
        }
        sw[wid][lane] = w;
    }
    __syncthreads();

    float sumw = 0.f;
    #pragma unroll
    for (int k = 0; k < K_NBR; ++k) sumw += sw[wid][k];

    float agg = 0.f;
    #pragma unroll 8
    for (int k = 0; k < K_NBR; ++k) {
        long long id = snb[wid][k];
        agg = fmaf(sw[wid][k], Hbuf[id * 64 + lane], agg);
    }
    agg = agg / (sumw + 1e-6f);
    sa[wid][lane] = agg;
    __syncthreads();

    float acc = Wb[lane];
    #pragma unroll
    for (int c = 0; c < 64; ++c)
        acc = fmaf(sx[wid][c], sW[c * 64 + lane], acc);
    #pragma unroll
    for (int c = 0; c < 64; ++c)
        acc = fmaf(sa[wid][c], sW[(64 + c) * 64 + lane], acc);

    float o = leaky_f(acc);
    float ss = o * o;
    #pragma unroll
    for (int off = 32; off; off >>= 1)
        ss += __shfl_xor(ss, off);
    if (valid)
        OUT[(long long)n * 64 + lane] = o / (sqrtf(ss) + 1e-6f);
}

extern "C" void kernel_launch(void* const* d_in, const int* in_sizes, int n_in,
                              void* d_out, int out_size, void* d_ws, size_t ws_size,
                              hipStream_t stream)
{
    const float* emb  = (const float*)d_in[0];  // (1, N, 64)
    const float* wmat = (const float*)d_in[1];  // (N, N)
    const int*   nbr  = (const int*)  d_in[2];  // (N, 32) int32
    const float* Q0w  = (const float*)d_in[3];
    const float* Q0b  = (const float*)d_in[4];
    const float* W0w  = (const float*)d_in[5];
    const float* W0b  = (const float*)d_in[6];
    const float* Q1w  = (const float*)d_in[7];
    const float* Q1b  = (const float*)d_in[8];
    const float* W1w  = (const float*)d_in[9];
    const float* W1b  = (const float*)d_in[10];
    float* out = (float*)d_out;

    const int N = in_sizes[2] / K_NBR;          // 12000
    const size_t hbuf_bytes = (size_t)N * 64 * sizeof(float);
    const size_t wc_bytes   = (size_t)N * K_NBR * sizeof(float);

    float* hbuf   = (float*)d_ws;
    bool use_wc   = ws_size >= hbuf_bytes + wc_bytes;
    float* wcache = use_wc ? (float*)((char*)d_ws + hbuf_bytes) : nullptr;

    const int grid = (N + 3) / 4;

    // ---- layer 0 ----
    k_dense64<<<grid, 256, 0, stream>>>(emb, Q0w, Q0b, hbuf, N);
    k_conv  <<<grid, 256, 0, stream>>>(emb, hbuf, wmat, nbr, wcache, W0w, W0b, out, N, 0);
    // ---- layer 1 (in-place on out) ----
    k_dense64<<<grid, 256, 0, stream>>>(out, Q1w, Q1b, hbuf, N);
    k_conv  <<<grid, 256, 0, stream>>>(out, hbuf, wmat, nbr, wcache, W1w, W1b, out, N,
                                       use_wc ? 1 : 0);
}